// Round 1
// baseline (1796.190 us; speedup 1.0000x reference)
//
#include <hip/hip_runtime.h>

// GCN 2-layer: x[N,128] @ W1[128,128] -> sym-norm aggregate -> +b1 -> relu
//              -> @ W2[128,64] -> aggregate -> +b2 -> out[N,64]
// All fp32. Edge indices int32 (JAX x64-disabled default).

__global__ void zero_f32(float* __restrict__ p, int n) {
    int i = blockIdx.x * blockDim.x + threadIdx.x;
    if (i < n) p[i] = 0.0f;
}

__global__ void count_deg(const int* __restrict__ dst, float* __restrict__ deg, int E) {
    int e = blockIdx.x * blockDim.x + threadIdx.x;
    if (e < E) atomicAdd(&deg[dst[e]], 1.0f);
}

__global__ void make_dinv(float* __restrict__ deg, int n) {
    int i = blockIdx.x * blockDim.x + threadIdx.x;
    if (i < n) deg[i] = rsqrtf(deg[i] + 1.0f);
}

// C[n,OUT] = (RELU ? max(A,0) : A)[n,128] @ W[128,OUT]
// One wave processes 2 rows at a time. W staged in LDS; x-row broadcast via
// __shfl (compiles to v_readlane for unrolled constant k). W LDS reads are
// stride-1 across lanes -> 2-way bank aliasing only (free on gfx950).
template <int OUT, bool RELU>
__global__ __launch_bounds__(256) void gemm_rows(const float* __restrict__ A,
                                                 const float* __restrict__ W,
                                                 float* __restrict__ C, int n) {
    __shared__ float sW[128 * OUT];
    for (int i = threadIdx.x; i < 128 * OUT; i += 256) sW[i] = W[i];
    __syncthreads();

    const int lane  = threadIdx.x & 63;
    const int wave  = blockIdx.x * 4 + (threadIdx.x >> 6);
    const int nwave = gridDim.x * 4;

    for (int row = wave * 2; row < n; row += nwave * 2) {
        const float* Ar0 = A + (size_t)row * 128;
        const float* Ar1 = Ar0 + 128;
        float a0 = Ar0[lane], a1 = Ar0[lane + 64];
        float b0 = Ar1[lane], b1 = Ar1[lane + 64];
        if (RELU) {
            a0 = fmaxf(a0, 0.0f); a1 = fmaxf(a1, 0.0f);
            b0 = fmaxf(b0, 0.0f); b1 = fmaxf(b1, 0.0f);
        }
        float acc00 = 0.f, acc01 = 0.f;  // row,   cols [lane], [lane+64]
        float acc10 = 0.f, acc11 = 0.f;  // row+1
#pragma unroll
        for (int k = 0; k < 64; ++k) {
            float xa = __shfl(a0, k);
            float xb = __shfl(b0, k);
            float w0 = sW[k * OUT + lane];
            acc00 = fmaf(xa, w0, acc00);
            acc10 = fmaf(xb, w0, acc10);
            if constexpr (OUT == 128) {
                float w1 = sW[k * OUT + lane + 64];
                acc01 = fmaf(xa, w1, acc01);
                acc11 = fmaf(xb, w1, acc11);
            }
        }
#pragma unroll
        for (int k = 0; k < 64; ++k) {
            float xa = __shfl(a1, k);
            float xb = __shfl(b1, k);
            float w0 = sW[(k + 64) * OUT + lane];
            acc00 = fmaf(xa, w0, acc00);
            acc10 = fmaf(xb, w0, acc10);
            if constexpr (OUT == 128) {
                float w1 = sW[(k + 64) * OUT + lane + 64];
                acc01 = fmaf(xa, w1, acc01);
                acc11 = fmaf(xb, w1, acc11);
            }
        }
        float* Cr0 = C + (size_t)row * OUT;
        float* Cr1 = Cr0 + OUT;
        Cr0[lane] = acc00;
        Cr1[lane] = acc10;
        if constexpr (OUT == 128) {
            Cr0[lane + 64] = acc01;
            Cr1[lane + 64] = acc11;
        }
    }
}

// agg[i] = h[i] * dinv[node]^2 + bias[f]   (self-loop term + bias)
template <int F>
__global__ void init_agg(const float* __restrict__ h, const float* __restrict__ dinv,
                         const float* __restrict__ bias, float* __restrict__ agg, int n) {
    int i = blockIdx.x * blockDim.x + threadIdx.x;
    if (i < n * F) {
        int node = i / F;
        int f    = i & (F - 1);
        float d  = dinv[node];
        agg[i]   = fmaf(h[i], d * d, bias[f]);
    }
}

// For each edge e: agg[dst[e], :] += dinv[src]*dinv[dst] * h[src[e], :]
template <int F>
__global__ __launch_bounds__(256) void scatter_edges(const float* __restrict__ h,
                                                     const float* __restrict__ dinv,
                                                     const int* __restrict__ src,
                                                     const int* __restrict__ dst,
                                                     float* __restrict__ agg, int E) {
    constexpr int EPB = 256 / F;
    int e = blockIdx.x * EPB + (threadIdx.x >> (F == 128 ? 7 : 6));
    if (e >= E) return;
    int f = threadIdx.x & (F - 1);
    int s = src[e];
    int d = dst[e];
    float w = dinv[s] * dinv[d];
    atomicAdd(&agg[(size_t)d * F + f], w * h[(size_t)s * F + f]);
}

extern "C" void kernel_launch(void* const* d_in, const int* in_sizes, int n_in,
                              void* d_out, int out_size, void* d_ws, size_t ws_size,
                              hipStream_t stream) {
    const float* x  = (const float*)d_in[0];
    const int*   ei = (const int*)d_in[1];
    const float* W1 = (const float*)d_in[2];
    const float* b1 = (const float*)d_in[3];
    const float* W2 = (const float*)d_in[4];
    const float* b2 = (const float*)d_in[5];
    float*       out = (float*)d_out;

    const int n = in_sizes[0] / 128;   // 100000
    const int E = in_sizes[1] / 2;     // 1600000
    const int* srcv = ei;              // edge_index[0]
    const int* dstv = ei + E;          // edge_index[1]

    float* ws   = (float*)d_ws;
    float* dinv = ws;
    size_t o1   = ((size_t)n + 511) & ~(size_t)511;
    float* h1   = ws + o1;                      // n*128
    float* agg1 = h1 + (size_t)n * 128;         // n*128
    float* h2   = h1;                           // reuse h1 region after layer-1 scatter

    // --- degree / dinv ---
    zero_f32<<<(n + 255) / 256, 256, 0, stream>>>(dinv, n);
    count_deg<<<(E + 255) / 256, 256, 0, stream>>>(dstv, dinv, E);
    make_dinv<<<(n + 255) / 256, 256, 0, stream>>>(dinv, n);

    // --- layer 1 ---
    gemm_rows<128, false><<<1024, 256, 0, stream>>>(x, W1, h1, n);
    init_agg<128><<<((size_t)n * 128 + 255) / 256, 256, 0, stream>>>(h1, dinv, b1, agg1, n);
    scatter_edges<128><<<(E + 1) / 2, 256, 0, stream>>>(h1, dinv, srcv, dstv, agg1, E);

    // --- layer 2 (relu fused into GEMM A-load) ---
    gemm_rows<64, true><<<1024, 256, 0, stream>>>(agg1, W2, h2, n);
    init_agg<64><<<((size_t)n * 64 + 255) / 256, 256, 0, stream>>>(h2, dinv, b2, out, n);
    scatter_edges<64><<<(E + 3) / 4, 256, 0, stream>>>(h2, dinv, srcv, dstv, out, E);
}

// Round 2
// 1137.881 us; speedup vs baseline: 1.5785x; 1.5785x over previous
//
#include <hip/hip_runtime.h>

// GCN 2-layer, CSR-gather formulation (no fp32 atomics on the feature matrix).
// Pipeline: hist(dst) -> scan(row_ptr,dinv) -> fill CSR {src, w=dinv_s*dinv_d}
//           -> h1 = x@W1 -> agg1 = gather(h1) (+self,+b1)
//           -> h2 = relu(agg1)@W2 -> out = gather(h2) (+self,+b2)

__global__ void zero_i32(int* __restrict__ p, int n) {
    int i = blockIdx.x * blockDim.x + threadIdx.x;
    if (i < n) p[i] = 0;
}

__global__ void hist_dst(const int* __restrict__ dst, int* __restrict__ cnt, int E) {
    int e = blockIdx.x * blockDim.x + threadIdx.x;
    if (e < E) atomicAdd(&cnt[dst[e]], 1);
}

// Single-block exclusive scan over cnt[n] -> row_ptr[n+1]; also cursor copy and
// dinv = rsqrt(cnt+1). Wave-level shfl scan + 16-wave LDS combine, serial carry.
__global__ __launch_bounds__(1024) void scan_build(const int* __restrict__ cnt,
                                                   int* __restrict__ row_ptr,
                                                   int* __restrict__ cursor,
                                                   float* __restrict__ dinv, int n) {
    __shared__ int wsum[16];
    __shared__ int s_carry;
    const int lane = threadIdx.x & 63;
    const int wid  = threadIdx.x >> 6;
    if (threadIdx.x == 0) s_carry = 0;
    __syncthreads();
    for (int base = 0; base < n; base += 1024) {
        int i = base + threadIdx.x;
        int v = (i < n) ? cnt[i] : 0;
        int x = v;
#pragma unroll
        for (int off = 1; off < 64; off <<= 1) {
            int t = __shfl_up(x, off);
            if (lane >= off) x += t;
        }
        if (lane == 63) wsum[wid] = x;
        __syncthreads();
        if (wid == 0 && lane < 16) {
            int w = wsum[lane];
#pragma unroll
            for (int off = 1; off < 16; off <<= 1) {
                int t = __shfl_up(w, off);
                if (lane >= off) w += t;
            }
            wsum[lane] = w;
        }
        __syncthreads();
        int wave_excl = (wid == 0) ? 0 : wsum[wid - 1];
        int incl = s_carry + wave_excl + x;
        if (i < n) {
            int excl   = incl - v;
            row_ptr[i] = excl;
            cursor[i]  = excl;
            dinv[i]    = rsqrtf((float)v + 1.0f);
        }
        __syncthreads();
        if (threadIdx.x == 1023) s_carry = incl;
        __syncthreads();
    }
    if (threadIdx.x == 0) row_ptr[n] = s_carry;
}

// CSR fill: ew[pos] = {src, bits(dinv[src]*dinv[dst])}
__global__ void fill_csr(const int* __restrict__ src, const int* __restrict__ dst,
                         const float* __restrict__ dinv, int* __restrict__ cursor,
                         int2* __restrict__ ew, int E) {
    int e = blockIdx.x * blockDim.x + threadIdx.x;
    if (e < E) {
        int s = src[e];
        int d = dst[e];
        int pos = atomicAdd(&cursor[d], 1);
        float w = dinv[s] * dinv[d];
        ew[pos] = make_int2(s, __float_as_int(w));
    }
}

// C[n,OUT] = (RELU ? max(A,0) : A)[n,128] @ W[128,OUT]
template <int OUT, bool RELU>
__global__ __launch_bounds__(256) void gemm_rows(const float* __restrict__ A,
                                                 const float* __restrict__ W,
                                                 float* __restrict__ C, int n) {
    __shared__ float sW[128 * OUT];
    for (int i = threadIdx.x; i < 128 * OUT; i += 256) sW[i] = W[i];
    __syncthreads();

    const int lane  = threadIdx.x & 63;
    const int wave  = blockIdx.x * 4 + (threadIdx.x >> 6);
    const int nwave = gridDim.x * 4;

    for (int row = wave * 2; row < n; row += nwave * 2) {
        const float* Ar0 = A + (size_t)row * 128;
        const float* Ar1 = Ar0 + 128;
        float a0 = Ar0[lane], a1 = Ar0[lane + 64];
        float b0 = Ar1[lane], b1 = Ar1[lane + 64];
        if (RELU) {
            a0 = fmaxf(a0, 0.0f); a1 = fmaxf(a1, 0.0f);
            b0 = fmaxf(b0, 0.0f); b1 = fmaxf(b1, 0.0f);
        }
        float acc00 = 0.f, acc01 = 0.f;
        float acc10 = 0.f, acc11 = 0.f;
#pragma unroll
        for (int k = 0; k < 64; ++k) {
            float xa = __shfl(a0, k);
            float xb = __shfl(b0, k);
            float w0 = sW[k * OUT + lane];
            acc00 = fmaf(xa, w0, acc00);
            acc10 = fmaf(xb, w0, acc10);
            if constexpr (OUT == 128) {
                float w1 = sW[k * OUT + lane + 64];
                acc01 = fmaf(xa, w1, acc01);
                acc11 = fmaf(xb, w1, acc11);
            }
        }
#pragma unroll
        for (int k = 0; k < 64; ++k) {
            float xa = __shfl(a1, k);
            float xb = __shfl(b1, k);
            float w0 = sW[(k + 64) * OUT + lane];
            acc00 = fmaf(xa, w0, acc00);
            acc10 = fmaf(xb, w0, acc10);
            if constexpr (OUT == 128) {
                float w1 = sW[(k + 64) * OUT + lane + 64];
                acc01 = fmaf(xa, w1, acc01);
                acc11 = fmaf(xb, w1, acc11);
            }
        }
        float* Cr0 = C + (size_t)row * OUT;
        float* Cr1 = Cr0 + OUT;
        Cr0[lane] = acc00;
        Cr1[lane] = acc10;
        if constexpr (OUT == 128) {
            Cr0[lane + 64] = acc01;
            Cr1[lane + 64] = acc11;
        }
    }
}

// One wave per node: out[node,:] = sum_{e in-edges} w_e * h[src_e,:]
//                                + dinv[node]^2 * h[node,:] + bias
template <int F>
__global__ __launch_bounds__(256) void gather_nodes(const float* __restrict__ h,
                                                    const float* __restrict__ dinv,
                                                    const int* __restrict__ row_ptr,
                                                    const int2* __restrict__ ew,
                                                    const float* __restrict__ bias,
                                                    float* __restrict__ outp, int n) {
    const int lane = threadIdx.x & 63;
    const int node = blockIdx.x * 4 + (threadIdx.x >> 6);
    if (node >= n) return;

    const float dd  = dinv[node];
    const int   beg = row_ptr[node];
    const int   end = row_ptr[node + 1];

    const float* hr = h + (size_t)node * F;
    float acc0 = fmaf(hr[lane] * dd, dd, bias[lane]);
    float acc1 = 0.0f;
    if constexpr (F == 128) acc1 = fmaf(hr[lane + 64] * dd, dd, bias[lane + 64]);

    int j = beg;
    for (; j + 1 < end; j += 2) {
        int2 e0 = ew[j];
        int2 e1 = ew[j + 1];
        const float* h0 = h + (size_t)e0.x * F;
        const float* h1 = h + (size_t)e1.x * F;
        float w0 = __int_as_float(e0.y);
        float w1 = __int_as_float(e1.y);
        float v00 = h0[lane];
        float v10 = h1[lane];
        acc0 = fmaf(w0, v00, acc0);
        acc0 = fmaf(w1, v10, acc0);
        if constexpr (F == 128) {
            float v01 = h0[lane + 64];
            float v11 = h1[lane + 64];
            acc1 = fmaf(w0, v01, acc1);
            acc1 = fmaf(w1, v11, acc1);
        }
    }
    if (j < end) {
        int2 e0 = ew[j];
        const float* h0 = h + (size_t)e0.x * F;
        float w0 = __int_as_float(e0.y);
        acc0 = fmaf(w0, h0[lane], acc0);
        if constexpr (F == 128) acc1 = fmaf(w0, h0[lane + 64], acc1);
    }

    float* o = outp + (size_t)node * F;
    o[lane] = acc0;
    if constexpr (F == 128) o[lane + 64] = acc1;
}

extern "C" void kernel_launch(void* const* d_in, const int* in_sizes, int n_in,
                              void* d_out, int out_size, void* d_ws, size_t ws_size,
                              hipStream_t stream) {
    const float* x  = (const float*)d_in[0];
    const int*   ei = (const int*)d_in[1];
    const float* W1 = (const float*)d_in[2];
    const float* b1 = (const float*)d_in[3];
    const float* W2 = (const float*)d_in[4];
    const float* b2 = (const float*)d_in[5];
    float*       out = (float*)d_out;

    const int n = in_sizes[0] / 128;   // 100000
    const int E = in_sizes[1] / 2;     // 1600000
    const int* srcv = ei;
    const int* dstv = ei + E;

    // workspace layout (4B elements)
    const int NP = 102400;             // >= n+1, aligned
    float* wsf     = (float*)d_ws;
    float* dinv    = wsf;                          // [0, NP)
    int*   row_ptr = (int*)(wsf + NP);             // [NP, 2NP)
    int2*  ew      = (int2*)(wsf + 2 * NP);        // E int2 -> 2E elems (8B-aligned)
    float* h1      = wsf + 2 * (size_t)NP + 2 * (size_t)E;  // n*128
    float* agg1    = h1 + (size_t)n * 128;                  // n*128
    float* h2      = h1;                                    // reuse after layer-1 gather
    // cnt/cursor overlay h1's region (dead before gemm1 writes h1)
    int* cnt    = (int*)h1;
    int* cursor = cnt + NP;

    // --- CSR build ---
    zero_i32<<<(n + 255) / 256, 256, 0, stream>>>(cnt, n);
    hist_dst<<<(E + 255) / 256, 256, 0, stream>>>(dstv, cnt, E);
    scan_build<<<1, 1024, 0, stream>>>(cnt, row_ptr, cursor, dinv, n);
    fill_csr<<<(E + 255) / 256, 256, 0, stream>>>(srcv, dstv, dinv, cursor, ew, E);

    // --- layer 1 ---
    gemm_rows<128, false><<<1024, 256, 0, stream>>>(x, W1, h1, n);
    gather_nodes<128><<<(n + 3) / 4, 256, 0, stream>>>(h1, dinv, row_ptr, ew, b1, agg1, n);

    // --- layer 2 ---
    gemm_rows<64, true><<<1024, 256, 0, stream>>>(agg1, W2, h2, n);
    gather_nodes<64><<<(n + 3) / 4, 256, 0, stream>>>(h2, dinv, row_ptr, ew, b2, out, n);
}

// Round 3
// 657.993 us; speedup vs baseline: 2.7298x; 1.7293x over previous
//
#include <hip/hip_runtime.h>

// GCN 2-layer, CSR-gather + register-tiled fp32 GEMM.
// R3: replaced shfl-broadcast GEMM (LDS-pipe-bound, 445us) with 128xOUT block
// tile, BK=16, 8x8 micro-tile. All LDS fragment reads are b128 at <=2-way bank
// aliasing (free on gfx950 per m136); A-reads broadcast across 16 lanes.

__global__ void zero_i32(int* __restrict__ p, int n) {
    int i = blockIdx.x * blockDim.x + threadIdx.x;
    if (i < n) p[i] = 0;
}

__global__ void hist_dst(const int* __restrict__ dst, int* __restrict__ cnt, int E) {
    int e = blockIdx.x * blockDim.x + threadIdx.x;
    if (e < E) atomicAdd(&cnt[dst[e]], 1);
}

// Single-block exclusive scan over cnt[n] -> row_ptr[n+1]; cursor copy; dinv.
__global__ __launch_bounds__(1024) void scan_build(const int* __restrict__ cnt,
                                                   int* __restrict__ row_ptr,
                                                   int* __restrict__ cursor,
                                                   float* __restrict__ dinv, int n) {
    __shared__ int wsum[16];
    __shared__ int s_carry;
    const int lane = threadIdx.x & 63;
    const int wid  = threadIdx.x >> 6;
    if (threadIdx.x == 0) s_carry = 0;
    __syncthreads();
    for (int base = 0; base < n; base += 1024) {
        int i = base + threadIdx.x;
        int v = (i < n) ? cnt[i] : 0;
        int x = v;
#pragma unroll
        for (int off = 1; off < 64; off <<= 1) {
            int t = __shfl_up(x, off);
            if (lane >= off) x += t;
        }
        if (lane == 63) wsum[wid] = x;
        __syncthreads();
        if (wid == 0 && lane < 16) {
            int w = wsum[lane];
#pragma unroll
            for (int off = 1; off < 16; off <<= 1) {
                int t = __shfl_up(w, off);
                if (lane >= off) w += t;
            }
            wsum[lane] = w;
        }
        __syncthreads();
        int wave_excl = (wid == 0) ? 0 : wsum[wid - 1];
        int incl = s_carry + wave_excl + x;
        if (i < n) {
            int excl   = incl - v;
            row_ptr[i] = excl;
            cursor[i]  = excl;
            dinv[i]    = rsqrtf((float)v + 1.0f);
        }
        __syncthreads();
        if (threadIdx.x == 1023) s_carry = incl;
        __syncthreads();
    }
    if (threadIdx.x == 0) row_ptr[n] = s_carry;
}

__global__ void fill_csr(const int* __restrict__ src, const int* __restrict__ dst,
                         const float* __restrict__ dinv, int* __restrict__ cursor,
                         int2* __restrict__ ew, int E) {
    int e = blockIdx.x * blockDim.x + threadIdx.x;
    if (e < E) {
        int s = src[e];
        int d = dst[e];
        int pos = atomicAdd(&cursor[d], 1);
        float w = dinv[s] * dinv[d];
        ew[pos] = make_int2(s, __float_as_int(w));
    }
}

// C[n,OUT] = (RELU ? max(A,0) : A)[n,128] @ W[128,OUT], K=128 fixed.
// Block: 256 threads = 16 tx * 16 ty. Tile: 128 rows x OUT cols, BK=16.
// Thread micro-tile: rows {4ty+i, 64+4ty+i}, cols {4tx+j [, 64+4tx+j]}.
template <int OUT, bool RELU>
__global__ __launch_bounds__(256) void gemm_tiled(const float* __restrict__ A,
                                                  const float* __restrict__ W,
                                                  float* __restrict__ C, int n) {
    constexpr int PA = 132;        // As pitch (words): 132 % 4 == 0, bank-spreads
    constexpr int PW = OUT + 4;    // Ws pitch
    constexpr int CN = (OUT == 128) ? 8 : 4;  // cols per thread
    __shared__ float As[16 * PA];  // As[k][row]
    __shared__ float Ws[16 * PW];  // Ws[k][col]

    const int t  = threadIdx.x;
    const int tx = t & 15;
    const int ty = t >> 4;
    const int row0 = blockIdx.x * 128;

    float acc[8][CN];
#pragma unroll
    for (int i = 0; i < 8; ++i)
#pragma unroll
        for (int j = 0; j < CN; ++j) acc[i][j] = 0.0f;

    for (int ck = 0; ck < 8; ++ck) {
        const int k0 = ck * 16;
        // --- stage A: As[k][row], transposed. 2 float4 per thread. ---
#pragma unroll
        for (int it = 0; it < 2; ++it) {
            int id  = t + it * 256;
            int row = id & 127;
            int q   = id >> 7;       // k-quad 0..3
            int grow = row0 + row;
            float4 v = make_float4(0.f, 0.f, 0.f, 0.f);
            if (grow < n) v = *(const float4*)(A + (size_t)grow * 128 + k0 + 4 * q);
            if (RELU) {
                v.x = fmaxf(v.x, 0.f); v.y = fmaxf(v.y, 0.f);
                v.z = fmaxf(v.z, 0.f); v.w = fmaxf(v.w, 0.f);
            }
            As[(4 * q + 0) * PA + row] = v.x;
            As[(4 * q + 1) * PA + row] = v.y;
            As[(4 * q + 2) * PA + row] = v.z;
            As[(4 * q + 3) * PA + row] = v.w;
        }
        // --- stage W: Ws[k][col]. ---
        constexpr int NF4 = OUT / 4;          // float4 per W row
        constexpr int NIT = (16 * NF4) / 256; // 2 (OUT=128) or 1 (OUT=64)
#pragma unroll
        for (int it = 0; it < NIT; ++it) {
            int id = t + it * 256;
            int c4 = id % NF4;
            int k  = id / NF4;
            float4 wv = *(const float4*)(W + (size_t)(k0 + k) * OUT + 4 * c4);
            *(float4*)(&Ws[k * PW + 4 * c4]) = wv;
        }
        __syncthreads();

        // --- inner product over this k-chunk ---
#pragma unroll
        for (int kk = 0; kk < 16; ++kk) {
            const float* as = &As[kk * PA + 4 * ty];
            float4 a0 = *(const float4*)(as);
            float4 a1 = *(const float4*)(as + 64);
            float av[8] = {a0.x, a0.y, a0.z, a0.w, a1.x, a1.y, a1.z, a1.w};
            const float* wr = &Ws[kk * PW + 4 * tx];
            float4 w0 = *(const float4*)(wr);
            float wv[CN];
            wv[0] = w0.x; wv[1] = w0.y; wv[2] = w0.z; wv[3] = w0.w;
            if constexpr (OUT == 128) {
                float4 w1 = *(const float4*)(wr + 64);
                wv[4] = w1.x; wv[5] = w1.y; wv[6] = w1.z; wv[7] = w1.w;
            }
#pragma unroll
            for (int i = 0; i < 8; ++i)
#pragma unroll
                for (int j = 0; j < CN; ++j)
                    acc[i][j] = fmaf(av[i], wv[j], acc[i][j]);
        }
        __syncthreads();
    }

    // --- store C ---
#pragma unroll
    for (int i = 0; i < 8; ++i) {
        int row = row0 + 4 * ty + ((i < 4) ? i : 60 + i);  // i>=4 -> 64+4ty+(i-4)
        if (row < n) {
            float* cp = C + (size_t)row * OUT + 4 * tx;
            *(float4*)(cp) = make_float4(acc[i][0], acc[i][1], acc[i][2], acc[i][3]);
            if constexpr (OUT == 128)
                *(float4*)(cp + 64) = make_float4(acc[i][4], acc[i][5], acc[i][6], acc[i][7]);
        }
    }
}

// One wave per node: out[node,:] = sum_e w_e * h[src_e,:] + dinv^2*h[node,:] + b
template <int F>
__global__ __launch_bounds__(256) void gather_nodes(const float* __restrict__ h,
                                                    const float* __restrict__ dinv,
                                                    const int* __restrict__ row_ptr,
                                                    const int2* __restrict__ ew,
                                                    const float* __restrict__ bias,
                                                    float* __restrict__ outp, int n) {
    const int lane = threadIdx.x & 63;
    const int node = blockIdx.x * 4 + (threadIdx.x >> 6);
    if (node >= n) return;

    const float dd  = dinv[node];
    const int   beg = row_ptr[node];
    const int   end = row_ptr[node + 1];

    const float* hr = h + (size_t)node * F;
    float acc0 = fmaf(hr[lane] * dd, dd, bias[lane]);
    float acc1 = 0.0f;
    if constexpr (F == 128) acc1 = fmaf(hr[lane + 64] * dd, dd, bias[lane + 64]);

    int j = beg;
    for (; j + 1 < end; j += 2) {
        int2 e0 = ew[j];
        int2 e1 = ew[j + 1];
        const float* h0 = h + (size_t)e0.x * F;
        const float* h1 = h + (size_t)e1.x * F;
        float w0 = __int_as_float(e0.y);
        float w1 = __int_as_float(e1.y);
        acc0 = fmaf(w0, h0[lane], acc0);
        acc0 = fmaf(w1, h1[lane], acc0);
        if constexpr (F == 128) {
            acc1 = fmaf(w0, h0[lane + 64], acc1);
            acc1 = fmaf(w1, h1[lane + 64], acc1);
        }
    }
    if (j < end) {
        int2 e0 = ew[j];
        const float* h0 = h + (size_t)e0.x * F;
        float w0 = __int_as_float(e0.y);
        acc0 = fmaf(w0, h0[lane], acc0);
        if constexpr (F == 128) acc1 = fmaf(w0, h0[lane + 64], acc1);
    }

    float* o = outp + (size_t)node * F;
    o[lane] = acc0;
    if constexpr (F == 128) o[lane + 64] = acc1;
}

extern "C" void kernel_launch(void* const* d_in, const int* in_sizes, int n_in,
                              void* d_out, int out_size, void* d_ws, size_t ws_size,
                              hipStream_t stream) {
    const float* x  = (const float*)d_in[0];
    const int*   ei = (const int*)d_in[1];
    const float* W1 = (const float*)d_in[2];
    const float* b1 = (const float*)d_in[3];
    const float* W2 = (const float*)d_in[4];
    const float* b2 = (const float*)d_in[5];
    float*       out = (float*)d_out;

    const int n = in_sizes[0] / 128;   // 100000
    const int E = in_sizes[1] / 2;     // 1600000
    const int* srcv = ei;
    const int* dstv = ei + E;

    const int NP = 102400;
    float* wsf     = (float*)d_ws;
    float* dinv    = wsf;
    int*   row_ptr = (int*)(wsf + NP);
    int2*  ew      = (int2*)(wsf + 2 * NP);
    float* h1      = wsf + 2 * (size_t)NP + 2 * (size_t)E;
    float* agg1    = h1 + (size_t)n * 128;
    float* h2      = h1;
    int* cnt    = (int*)h1;     // overlays h1 (dead until gemm1)
    int* cursor = cnt + NP;

    // --- CSR build ---
    zero_i32<<<(n + 255) / 256, 256, 0, stream>>>(cnt, n);
    hist_dst<<<(E + 255) / 256, 256, 0, stream>>>(dstv, cnt, E);
    scan_build<<<1, 1024, 0, stream>>>(cnt, row_ptr, cursor, dinv, n);
    fill_csr<<<(E + 255) / 256, 256, 0, stream>>>(srcv, dstv, dinv, cursor, ew, E);

    const int gblocks = (n + 127) / 128;  // 782
    // --- layer 1 ---
    gemm_tiled<128, false><<<gblocks, 256, 0, stream>>>(x, W1, h1, n);
    gather_nodes<128><<<(n + 3) / 4, 256, 0, stream>>>(h1, dinv, row_ptr, ew, b1, agg1, n);

    // --- layer 2 ---
    gemm_tiled<64, true><<<gblocks, 256, 0, stream>>>(agg1, W2, h2, n);
    gather_nodes<64><<<(n + 3) / 4, 256, 0, stream>>>(h2, dinv, row_ptr, ew, b2, out, n);
}

// Round 4
// 567.706 us; speedup vs baseline: 3.1639x; 1.1590x over previous
//
#include <hip/hip_runtime.h>

// GCN 2-layer, CSR-gather + register-tiled fp32 GEMM + bf16 feature storage.
// R4: h1/h2 stored as packed bf16 pairs (RNE) -> halves random gather traffic
// (the bottleneck: 405MB FETCH_SIZE on gather<128>, ~50% L2 hit at fp32).
// Accumulation stays fp32; agg1 (gemm2 input) stays fp32.

typedef unsigned int u32;

__device__ inline u32 pack_bf16(float a, float b) {
    u32 ua = __float_as_uint(a);
    u32 ub = __float_as_uint(b);
    ua += 0x7fffu + ((ua >> 16) & 1u);   // RNE
    ub += 0x7fffu + ((ub >> 16) & 1u);
    return (ua >> 16) | (ub & 0xffff0000u);
}
__device__ inline float bf_lo(u32 v) { return __uint_as_float(v << 16); }
__device__ inline float bf_hi(u32 v) { return __uint_as_float(v & 0xffff0000u); }

__global__ void zero_i32(int* __restrict__ p, int n) {
    int i = blockIdx.x * blockDim.x + threadIdx.x;
    if (i < n) p[i] = 0;
}

__global__ void hist_dst(const int* __restrict__ dst, int* __restrict__ cnt, int E) {
    int e = blockIdx.x * blockDim.x + threadIdx.x;
    if (e < E) atomicAdd(&cnt[dst[e]], 1);
}

// Single-block exclusive scan over cnt[n] -> row_ptr[n+1]; cursor copy; dinv.
__global__ __launch_bounds__(1024) void scan_build(const int* __restrict__ cnt,
                                                   int* __restrict__ row_ptr,
                                                   int* __restrict__ cursor,
                                                   float* __restrict__ dinv, int n) {
    __shared__ int wsum[16];
    __shared__ int s_carry;
    const int lane = threadIdx.x & 63;
    const int wid  = threadIdx.x >> 6;
    if (threadIdx.x == 0) s_carry = 0;
    __syncthreads();
    for (int base = 0; base < n; base += 1024) {
        int i = base + threadIdx.x;
        int v = (i < n) ? cnt[i] : 0;
        int x = v;
#pragma unroll
        for (int off = 1; off < 64; off <<= 1) {
            int t = __shfl_up(x, off);
            if (lane >= off) x += t;
        }
        if (lane == 63) wsum[wid] = x;
        __syncthreads();
        if (wid == 0 && lane < 16) {
            int w = wsum[lane];
#pragma unroll
            for (int off = 1; off < 16; off <<= 1) {
                int t = __shfl_up(w, off);
                if (lane >= off) w += t;
            }
            wsum[lane] = w;
        }
        __syncthreads();
        int wave_excl = (wid == 0) ? 0 : wsum[wid - 1];
        int incl = s_carry + wave_excl + x;
        if (i < n) {
            int excl   = incl - v;
            row_ptr[i] = excl;
            cursor[i]  = excl;
            dinv[i]    = rsqrtf((float)v + 1.0f);
        }
        __syncthreads();
        if (threadIdx.x == 1023) s_carry = incl;
        __syncthreads();
    }
    if (threadIdx.x == 0) row_ptr[n] = s_carry;
}

__global__ void fill_csr(const int* __restrict__ src, const int* __restrict__ dst,
                         const float* __restrict__ dinv, int* __restrict__ cursor,
                         int2* __restrict__ ew, int E) {
    int e = blockIdx.x * blockDim.x + threadIdx.x;
    if (e < E) {
        int s = src[e];
        int d = dst[e];
        int pos = atomicAdd(&cursor[d], 1);
        float w = dinv[s] * dinv[d];
        ew[pos] = make_int2(s, __float_as_int(w));
    }
}

// C[n,OUT](bf16 pairs) = (RELU ? max(A,0) : A)[n,128](f32) @ W[128,OUT](f32)
template <int OUT, bool RELU>
__global__ __launch_bounds__(256) void gemm_tiled(const float* __restrict__ A,
                                                  const float* __restrict__ W,
                                                  u32* __restrict__ C, int n) {
    constexpr int PA = 132;
    constexpr int PW = OUT + 4;
    constexpr int CN = (OUT == 128) ? 8 : 4;
    __shared__ float As[16 * PA];  // As[k][row]
    __shared__ float Ws[16 * PW];  // Ws[k][col]

    const int t  = threadIdx.x;
    const int tx = t & 15;
    const int ty = t >> 4;
    const int row0 = blockIdx.x * 128;

    float acc[8][CN];
#pragma unroll
    for (int i = 0; i < 8; ++i)
#pragma unroll
        for (int j = 0; j < CN; ++j) acc[i][j] = 0.0f;

    for (int ck = 0; ck < 8; ++ck) {
        const int k0 = ck * 16;
#pragma unroll
        for (int it = 0; it < 2; ++it) {
            int id  = t + it * 256;
            int row = id & 127;
            int q   = id >> 7;
            int grow = row0 + row;
            float4 v = make_float4(0.f, 0.f, 0.f, 0.f);
            if (grow < n) v = *(const float4*)(A + (size_t)grow * 128 + k0 + 4 * q);
            if (RELU) {
                v.x = fmaxf(v.x, 0.f); v.y = fmaxf(v.y, 0.f);
                v.z = fmaxf(v.z, 0.f); v.w = fmaxf(v.w, 0.f);
            }
            As[(4 * q + 0) * PA + row] = v.x;
            As[(4 * q + 1) * PA + row] = v.y;
            As[(4 * q + 2) * PA + row] = v.z;
            As[(4 * q + 3) * PA + row] = v.w;
        }
        constexpr int NF4 = OUT / 4;
        constexpr int NIT = (16 * NF4) / 256;
#pragma unroll
        for (int it = 0; it < NIT; ++it) {
            int id = t + it * 256;
            int c4 = id % NF4;
            int k  = id / NF4;
            float4 wv = *(const float4*)(W + (size_t)(k0 + k) * OUT + 4 * c4);
            *(float4*)(&Ws[k * PW + 4 * c4]) = wv;
        }
        __syncthreads();

#pragma unroll
        for (int kk = 0; kk < 16; ++kk) {
            const float* as = &As[kk * PA + 4 * ty];
            float4 a0 = *(const float4*)(as);
            float4 a1 = *(const float4*)(as + 64);
            float av[8] = {a0.x, a0.y, a0.z, a0.w, a1.x, a1.y, a1.z, a1.w};
            const float* wr = &Ws[kk * PW + 4 * tx];
            float4 w0 = *(const float4*)(wr);
            float wv[CN];
            wv[0] = w0.x; wv[1] = w0.y; wv[2] = w0.z; wv[3] = w0.w;
            if constexpr (OUT == 128) {
                float4 w1 = *(const float4*)(wr + 64);
                wv[4] = w1.x; wv[5] = w1.y; wv[6] = w1.z; wv[7] = w1.w;
            }
#pragma unroll
            for (int i = 0; i < 8; ++i)
#pragma unroll
                for (int j = 0; j < CN; ++j)
                    acc[i][j] = fmaf(av[i], wv[j], acc[i][j]);
        }
        __syncthreads();
    }

    // store C as packed bf16 pairs; row stride OUT/2 dwords
#pragma unroll
    for (int i = 0; i < 8; ++i) {
        int row = row0 + 4 * ty + ((i < 4) ? i : 60 + i);
        if (row < n) {
            u32* cp = C + (size_t)row * (OUT / 2) + 2 * tx;
            uint2 p0;
            p0.x = pack_bf16(acc[i][0], acc[i][1]);
            p0.y = pack_bf16(acc[i][2], acc[i][3]);
            *(uint2*)cp = p0;
            if constexpr (OUT == 128) {
                uint2 p1;
                p1.x = pack_bf16(acc[i][4], acc[i][5]);
                p1.y = pack_bf16(acc[i][6], acc[i][7]);
                *(uint2*)(cp + 32) = p1;
            }
        }
    }
}

// Layer-1 gather: one wave per node, F=128. h is bf16-pair packed [n][64] dwords.
// lane -> features {2*lane, 2*lane+1}. Output agg fp32.
__global__ __launch_bounds__(256) void gather128(const u32* __restrict__ h,
                                                 const float* __restrict__ dinv,
                                                 const int* __restrict__ row_ptr,
                                                 const int2* __restrict__ ew,
                                                 const float* __restrict__ bias,
                                                 float* __restrict__ outp, int n) {
    const int lane = threadIdx.x & 63;
    const int node = blockIdx.x * 4 + (threadIdx.x >> 6);
    if (node >= n) return;

    const float dd  = dinv[node];
    const int   beg = row_ptr[node];
    const int   end = row_ptr[node + 1];

    u32 sv = h[(size_t)node * 64 + lane];
    float2 b = ((const float2*)bias)[lane];
    float acc0 = fmaf(bf_lo(sv) * dd, dd, b.x);
    float acc1 = fmaf(bf_hi(sv) * dd, dd, b.y);

    for (int j = beg; j < end; j += 4) {
        int i1 = (j + 1 < end) ? j + 1 : end - 1;
        int i2 = (j + 2 < end) ? j + 2 : end - 1;
        int i3 = (j + 3 < end) ? j + 3 : end - 1;
        int2 e0 = ew[j];
        int2 e1 = ew[i1];
        int2 e2 = ew[i2];
        int2 e3 = ew[i3];
        float w0 = __int_as_float(e0.y);
        float w1 = (j + 1 < end) ? __int_as_float(e1.y) : 0.0f;
        float w2 = (j + 2 < end) ? __int_as_float(e2.y) : 0.0f;
        float w3 = (j + 3 < end) ? __int_as_float(e3.y) : 0.0f;
        u32 v0 = h[(size_t)e0.x * 64 + lane];
        u32 v1 = h[(size_t)e1.x * 64 + lane];
        u32 v2 = h[(size_t)e2.x * 64 + lane];
        u32 v3 = h[(size_t)e3.x * 64 + lane];
        acc0 = fmaf(w0, bf_lo(v0), acc0); acc1 = fmaf(w0, bf_hi(v0), acc1);
        acc0 = fmaf(w1, bf_lo(v1), acc0); acc1 = fmaf(w1, bf_hi(v1), acc1);
        acc0 = fmaf(w2, bf_lo(v2), acc0); acc1 = fmaf(w2, bf_hi(v2), acc1);
        acc0 = fmaf(w3, bf_lo(v3), acc0); acc1 = fmaf(w3, bf_hi(v3), acc1);
    }

    ((float2*)(outp + (size_t)node * 128))[lane] = make_float2(acc0, acc1);
}

// Layer-2 gather: one wave per node, F=64. h is bf16-pair packed [n][32] dwords.
// Two edges per wave-step: sub = lane>>5 picks the edge, lane&31 -> feature pair.
__global__ __launch_bounds__(256) void gather64(const u32* __restrict__ h,
                                                const float* __restrict__ dinv,
                                                const int* __restrict__ row_ptr,
                                                const int2* __restrict__ ew,
                                                const float* __restrict__ bias,
                                                float* __restrict__ outp, int n) {
    const int lane   = threadIdx.x & 63;
    const int lane32 = lane & 31;
    const int sub    = lane >> 5;
    const int node   = blockIdx.x * 4 + (threadIdx.x >> 6);
    if (node >= n) return;

    const float dd  = dinv[node];
    const int   beg = row_ptr[node];
    const int   end = row_ptr[node + 1];

    float acc0 = 0.0f, acc1 = 0.0f;
    if (sub == 0) {
        u32 sv = h[(size_t)node * 32 + lane32];
        float2 b = ((const float2*)bias)[lane32];
        acc0 = fmaf(bf_lo(sv) * dd, dd, b.x);
        acc1 = fmaf(bf_hi(sv) * dd, dd, b.y);
    }

    for (int j = beg; j < end; j += 4) {
        int i0 = j + sub;
        int i1 = j + 2 + sub;
        int c0 = (i0 < end) ? i0 : end - 1;
        int c1 = (i1 < end) ? i1 : end - 1;
        int2 e0 = ew[c0];
        int2 e1 = ew[c1];
        float w0 = (i0 < end) ? __int_as_float(e0.y) : 0.0f;
        float w1 = (i1 < end) ? __int_as_float(e1.y) : 0.0f;
        u32 v0 = h[(size_t)e0.x * 32 + lane32];
        u32 v1 = h[(size_t)e1.x * 32 + lane32];
        acc0 = fmaf(w0, bf_lo(v0), acc0); acc1 = fmaf(w0, bf_hi(v0), acc1);
        acc0 = fmaf(w1, bf_lo(v1), acc0); acc1 = fmaf(w1, bf_hi(v1), acc1);
    }

    acc0 += __shfl_xor(acc0, 32);
    acc1 += __shfl_xor(acc1, 32);
    if (sub == 0)
        ((float2*)(outp + (size_t)node * 64))[lane32] = make_float2(acc0, acc1);
}

extern "C" void kernel_launch(void* const* d_in, const int* in_sizes, int n_in,
                              void* d_out, int out_size, void* d_ws, size_t ws_size,
                              hipStream_t stream) {
    const float* x  = (const float*)d_in[0];
    const int*   ei = (const int*)d_in[1];
    const float* W1 = (const float*)d_in[2];
    const float* b1 = (const float*)d_in[3];
    const float* W2 = (const float*)d_in[4];
    const float* b2 = (const float*)d_in[5];
    float*       out = (float*)d_out;

    const int n = in_sizes[0] / 128;   // 100000
    const int E = in_sizes[1] / 2;     // 1600000
    const int* srcv = ei;
    const int* dstv = ei + E;

    const int NP = 102400;
    float* wsf     = (float*)d_ws;
    float* dinv    = wsf;                                   // NP f32
    int*   row_ptr = (int*)(wsf + NP);                      // NP i32
    int2*  ew      = (int2*)(wsf + 2 * NP);                 // E int2
    u32*   h1u     = (u32*)(wsf + 2 * (size_t)NP + 2 * (size_t)E);  // n*64 dwords
    float* agg1    = (float*)(h1u + (size_t)n * 64);        // n*128 f32
    u32*   h2u     = h1u;                                   // reuse (n*32 dwords)
    int* cnt    = (int*)h1u;   // overlays h1u (dead before gemm1 writes)
    int* cursor = cnt + NP;

    // --- CSR build ---
    zero_i32<<<(n + 255) / 256, 256, 0, stream>>>(cnt, n);
    hist_dst<<<(E + 255) / 256, 256, 0, stream>>>(dstv, cnt, E);
    scan_build<<<1, 1024, 0, stream>>>(cnt, row_ptr, cursor, dinv, n);
    fill_csr<<<(E + 255) / 256, 256, 0, stream>>>(srcv, dstv, dinv, cursor, ew, E);

    const int gblocks = (n + 127) / 128;
    // --- layer 1 ---
    gemm_tiled<128, false><<<gblocks, 256, 0, stream>>>(x, W1, h1u, n);
    gather128<<<(n + 3) / 4, 256, 0, stream>>>(h1u, dinv, row_ptr, ew, b1, agg1, n);

    // --- layer 2 ---
    gemm_tiled<64, true><<<gblocks, 256, 0, stream>>>(agg1, W2, h2u, n);
    gather64<<<(n + 3) / 4, 256, 0, stream>>>(h2u, dinv, row_ptr, ew, b2, out, n);
}

// Round 5
// 411.738 us; speedup vs baseline: 4.3625x; 1.3788x over previous
//
#include <hip/hip_runtime.h>

// GCN 2-layer. R5: CSR build restructured.
//  - hist fused with rank capture (one atomic sweep total, was two)
//  - multi-block scan (was single-block, 107us -> ~12us)
//  - placement pass is atomic-free: pos = row_ptr[dst] + rank[e]
//  - edge payload packed to 4B: src(17b) | w as custom f15 (4b exp, 11b man)
// Gathers read bf16-packed features (R4) + decode w in-register.

typedef unsigned int u32;

__device__ inline u32 pack_bf16(float a, float b) {
    u32 ua = __float_as_uint(a);
    u32 ub = __float_as_uint(b);
    ua += 0x7fffu + ((ua >> 16) & 1u);   // RNE
    ub += 0x7fffu + ((ub >> 16) & 1u);
    return (ua >> 16) | (ub & 0xffff0000u);
}
__device__ inline float bf_lo(u32 v) { return __uint_as_float(v << 16); }
__device__ inline float bf_hi(u32 v) { return __uint_as_float(v & 0xffff0000u); }

// w in (2^-16, 1] -> 15 bits: ec = 127-exp (4b), mantissa 11b
__device__ inline u32 pack_w(float w) {
    u32 b  = __float_as_uint(w) + 0x800u;   // round mantissa to 11 bits
    u32 e8 = b >> 23;
    u32 ec = 127u - e8;
    u32 m  = (b >> 12) & 0x7ffu;
    if (ec > 15u) { ec = 15u; m = 0u; }
    return (ec << 11) | m;
}
__device__ inline float dec_w(u32 u) {
    u32 wq = u & 0x7fffu;
    u32 e8 = 127u - (wq >> 11);
    return __uint_as_float((e8 << 23) | ((wq & 0x7ffu) << 12));
}

__global__ void zero_i32(int* __restrict__ p, int n) {
    int i = blockIdx.x * blockDim.x + threadIdx.x;
    if (i < n) p[i] = 0;
}

// histogram + per-edge rank in one pass
__global__ void hist_rank(const int* __restrict__ dst, int* __restrict__ cnt,
                          int* __restrict__ rank, int E) {
    int e = blockIdx.x * blockDim.x + threadIdx.x;
    if (e < E) rank[e] = atomicAdd(&cnt[dst[e]], 1);
}

// S1: per-block (1024 elems) reduce of cnt -> bsum[b]
__global__ __launch_bounds__(1024) void scan_reduce(const int* __restrict__ cnt,
                                                    int* __restrict__ bsum, int n) {
    __shared__ int wsum[16];
    int i = blockIdx.x * 1024 + threadIdx.x;
    int v = (i < n) ? cnt[i] : 0;
#pragma unroll
    for (int off = 32; off > 0; off >>= 1) v += __shfl_down(v, off);
    const int lane = threadIdx.x & 63;
    const int wid  = threadIdx.x >> 6;
    if (lane == 0) wsum[wid] = v;
    __syncthreads();
    if (threadIdx.x < 16) {
        int s = wsum[threadIdx.x];
#pragma unroll
        for (int off = 8; off > 0; off >>= 1) s += __shfl_down(s, off);
        if (threadIdx.x == 0) bsum[blockIdx.x] = s;
    }
}

// S2: single wave scans nb (<=128) partials -> exclusive boff; writes row_ptr[n]
__global__ void scan_partials(const int* __restrict__ bsum, int* __restrict__ boff,
                              int* __restrict__ row_ptr, int nb, int n) {
    const int lane = threadIdx.x;  // 64 threads
    int carry = 0;
    for (int base = 0; base < nb; base += 64) {
        int i = base + lane;
        int v = (i < nb) ? bsum[i] : 0;
        int x = v;
#pragma unroll
        for (int off = 1; off < 64; off <<= 1) {
            int t = __shfl_up(x, off);
            if (lane >= off) x += t;
        }
        if (i < nb) boff[i] = carry + x - v;
        carry += __shfl(x, 63);
    }
    if (lane == 0) row_ptr[n] = carry;
}

// S3: per-block exclusive scan + block offset -> row_ptr; also dinv
__global__ __launch_bounds__(1024) void scan_apply(const int* __restrict__ cnt,
                                                   const int* __restrict__ boff,
                                                   int* __restrict__ row_ptr,
                                                   float* __restrict__ dinv, int n) {
    __shared__ int wsum[16];
    const int lane = threadIdx.x & 63;
    const int wid  = threadIdx.x >> 6;
    int i = blockIdx.x * 1024 + threadIdx.x;
    int v = (i < n) ? cnt[i] : 0;
    int x = v;
#pragma unroll
    for (int off = 1; off < 64; off <<= 1) {
        int t = __shfl_up(x, off);
        if (lane >= off) x += t;
    }
    if (lane == 63) wsum[wid] = x;
    __syncthreads();
    if (wid == 0 && lane < 16) {
        int w = wsum[lane];
#pragma unroll
        for (int off = 1; off < 16; off <<= 1) {
            int t = __shfl_up(w, off);
            if (lane >= off) w += t;
        }
        wsum[lane] = w;
    }
    __syncthreads();
    int wave_excl = (wid == 0) ? 0 : wsum[wid - 1];
    if (i < n) {
        row_ptr[i] = boff[blockIdx.x] + wave_excl + (x - v);
        dinv[i]    = rsqrtf((float)v + 1.0f);
    }
}

// atomic-free placement: ew[row_ptr[d] + rank[e]] = src<<15 | pack_w(dinv_s*dinv_d)
__global__ void place_csr(const int* __restrict__ src, const int* __restrict__ dst,
                          const int* __restrict__ rank, const int* __restrict__ row_ptr,
                          const float* __restrict__ dinv, u32* __restrict__ ew, int E) {
    int e = blockIdx.x * blockDim.x + threadIdx.x;
    if (e < E) {
        int s = src[e];
        int d = dst[e];
        float w = dinv[s] * dinv[d];
        ew[row_ptr[d] + rank[e]] = ((u32)s << 15) | pack_w(w);
    }
}

// C[n,OUT](bf16 pairs) = (RELU ? max(A,0) : A)[n,128](f32) @ W[128,OUT](f32)
template <int OUT, bool RELU>
__global__ __launch_bounds__(256) void gemm_tiled(const float* __restrict__ A,
                                                  const float* __restrict__ W,
                                                  u32* __restrict__ C, int n) {
    constexpr int PA = 132;
    constexpr int PW = OUT + 4;
    constexpr int CN = (OUT == 128) ? 8 : 4;
    __shared__ float As[16 * PA];
    __shared__ float Ws[16 * PW];

    const int t  = threadIdx.x;
    const int tx = t & 15;
    const int ty = t >> 4;
    const int row0 = blockIdx.x * 128;

    float acc[8][CN];
#pragma unroll
    for (int i = 0; i < 8; ++i)
#pragma unroll
        for (int j = 0; j < CN; ++j) acc[i][j] = 0.0f;

    for (int ck = 0; ck < 8; ++ck) {
        const int k0 = ck * 16;
#pragma unroll
        for (int it = 0; it < 2; ++it) {
            int id  = t + it * 256;
            int row = id & 127;
            int q   = id >> 7;
            int grow = row0 + row;
            float4 v = make_float4(0.f, 0.f, 0.f, 0.f);
            if (grow < n) v = *(const float4*)(A + (size_t)grow * 128 + k0 + 4 * q);
            if (RELU) {
                v.x = fmaxf(v.x, 0.f); v.y = fmaxf(v.y, 0.f);
                v.z = fmaxf(v.z, 0.f); v.w = fmaxf(v.w, 0.f);
            }
            As[(4 * q + 0) * PA + row] = v.x;
            As[(4 * q + 1) * PA + row] = v.y;
            As[(4 * q + 2) * PA + row] = v.z;
            As[(4 * q + 3) * PA + row] = v.w;
        }
        constexpr int NF4 = OUT / 4;
        constexpr int NIT = (16 * NF4) / 256;
#pragma unroll
        for (int it = 0; it < NIT; ++it) {
            int id = t + it * 256;
            int c4 = id % NF4;
            int k  = id / NF4;
            float4 wv = *(const float4*)(W + (size_t)(k0 + k) * OUT + 4 * c4);
            *(float4*)(&Ws[k * PW + 4 * c4]) = wv;
        }
        __syncthreads();

#pragma unroll
        for (int kk = 0; kk < 16; ++kk) {
            const float* as = &As[kk * PA + 4 * ty];
            float4 a0 = *(const float4*)(as);
            float4 a1 = *(const float4*)(as + 64);
            float av[8] = {a0.x, a0.y, a0.z, a0.w, a1.x, a1.y, a1.z, a1.w};
            const float* wr = &Ws[kk * PW + 4 * tx];
            float4 w0 = *(const float4*)(wr);
            float wv[CN];
            wv[0] = w0.x; wv[1] = w0.y; wv[2] = w0.z; wv[3] = w0.w;
            if constexpr (OUT == 128) {
                float4 w1 = *(const float4*)(wr + 64);
                wv[4] = w1.x; wv[5] = w1.y; wv[6] = w1.z; wv[7] = w1.w;
            }
#pragma unroll
            for (int i = 0; i < 8; ++i)
#pragma unroll
                for (int j = 0; j < CN; ++j)
                    acc[i][j] = fmaf(av[i], wv[j], acc[i][j]);
        }
        __syncthreads();
    }

#pragma unroll
    for (int i = 0; i < 8; ++i) {
        int row = row0 + 4 * ty + ((i < 4) ? i : 60 + i);
        if (row < n) {
            u32* cp = C + (size_t)row * (OUT / 2) + 2 * tx;
            uint2 p0;
            p0.x = pack_bf16(acc[i][0], acc[i][1]);
            p0.y = pack_bf16(acc[i][2], acc[i][3]);
            *(uint2*)cp = p0;
            if constexpr (OUT == 128) {
                uint2 p1;
                p1.x = pack_bf16(acc[i][4], acc[i][5]);
                p1.y = pack_bf16(acc[i][6], acc[i][7]);
                *(uint2*)(cp + 32) = p1;
            }
        }
    }
}

// Layer-1 gather: one wave per node, F=128, h bf16-pair packed [n][64] dwords.
__global__ __launch_bounds__(256) void gather128(const u32* __restrict__ h,
                                                 const float* __restrict__ dinv,
                                                 const int* __restrict__ row_ptr,
                                                 const u32* __restrict__ ew,
                                                 const float* __restrict__ bias,
                                                 float* __restrict__ outp, int n) {
    const int lane = threadIdx.x & 63;
    const int node = blockIdx.x * 4 + (threadIdx.x >> 6);
    if (node >= n) return;

    const float dd  = dinv[node];
    const int   beg = row_ptr[node];
    const int   end = row_ptr[node + 1];

    u32 sv = h[(size_t)node * 64 + lane];
    float2 b = ((const float2*)bias)[lane];
    float acc0 = fmaf(bf_lo(sv) * dd, dd, b.x);
    float acc1 = fmaf(bf_hi(sv) * dd, dd, b.y);

    for (int j = beg; j < end; j += 4) {
        int i1 = (j + 1 < end) ? j + 1 : end - 1;
        int i2 = (j + 2 < end) ? j + 2 : end - 1;
        int i3 = (j + 3 < end) ? j + 3 : end - 1;
        u32 e0 = ew[j];
        u32 e1 = ew[i1];
        u32 e2 = ew[i2];
        u32 e3 = ew[i3];
        float w0 = dec_w(e0);
        float w1 = (j + 1 < end) ? dec_w(e1) : 0.0f;
        float w2 = (j + 2 < end) ? dec_w(e2) : 0.0f;
        float w3 = (j + 3 < end) ? dec_w(e3) : 0.0f;
        u32 v0 = h[(size_t)(e0 >> 15) * 64 + lane];
        u32 v1 = h[(size_t)(e1 >> 15) * 64 + lane];
        u32 v2 = h[(size_t)(e2 >> 15) * 64 + lane];
        u32 v3 = h[(size_t)(e3 >> 15) * 64 + lane];
        acc0 = fmaf(w0, bf_lo(v0), acc0); acc1 = fmaf(w0, bf_hi(v0), acc1);
        acc0 = fmaf(w1, bf_lo(v1), acc0); acc1 = fmaf(w1, bf_hi(v1), acc1);
        acc0 = fmaf(w2, bf_lo(v2), acc0); acc1 = fmaf(w2, bf_hi(v2), acc1);
        acc0 = fmaf(w3, bf_lo(v3), acc0); acc1 = fmaf(w3, bf_hi(v3), acc1);
    }

    ((float2*)(outp + (size_t)node * 128))[lane] = make_float2(acc0, acc1);
}

// Layer-2 gather: one wave per node, F=64, 2 edges per wave-step.
__global__ __launch_bounds__(256) void gather64(const u32* __restrict__ h,
                                                const float* __restrict__ dinv,
                                                const int* __restrict__ row_ptr,
                                                const u32* __restrict__ ew,
                                                const float* __restrict__ bias,
                                                float* __restrict__ outp, int n) {
    const int lane   = threadIdx.x & 63;
    const int lane32 = lane & 31;
    const int sub    = lane >> 5;
    const int node   = blockIdx.x * 4 + (threadIdx.x >> 6);
    if (node >= n) return;

    const float dd  = dinv[node];
    const int   beg = row_ptr[node];
    const int   end = row_ptr[node + 1];

    float acc0 = 0.0f, acc1 = 0.0f;
    if (sub == 0) {
        u32 sv = h[(size_t)node * 32 + lane32];
        float2 b = ((const float2*)bias)[lane32];
        acc0 = fmaf(bf_lo(sv) * dd, dd, b.x);
        acc1 = fmaf(bf_hi(sv) * dd, dd, b.y);
    }

    for (int j = beg; j < end; j += 4) {
        int i0 = j + sub;
        int i1 = j + 2 + sub;
        int c0 = (i0 < end) ? i0 : end - 1;
        int c1 = (i1 < end) ? i1 : end - 1;
        u32 e0 = ew[c0];
        u32 e1 = ew[c1];
        float w0 = (i0 < end) ? dec_w(e0) : 0.0f;
        float w1 = (i1 < end) ? dec_w(e1) : 0.0f;
        u32 v0 = h[(size_t)(e0 >> 15) * 32 + lane32];
        u32 v1 = h[(size_t)(e1 >> 15) * 32 + lane32];
        acc0 = fmaf(w0, bf_lo(v0), acc0); acc1 = fmaf(w0, bf_hi(v0), acc1);
        acc0 = fmaf(w1, bf_lo(v1), acc0); acc1 = fmaf(w1, bf_hi(v1), acc1);
    }

    acc0 += __shfl_xor(acc0, 32);
    acc1 += __shfl_xor(acc1, 32);
    if (sub == 0)
        ((float2*)(outp + (size_t)node * 64))[lane32] = make_float2(acc0, acc1);
}

extern "C" void kernel_launch(void* const* d_in, const int* in_sizes, int n_in,
                              void* d_out, int out_size, void* d_ws, size_t ws_size,
                              hipStream_t stream) {
    const float* x  = (const float*)d_in[0];
    const int*   ei = (const int*)d_in[1];
    const float* W1 = (const float*)d_in[2];
    const float* b1 = (const float*)d_in[3];
    const float* W2 = (const float*)d_in[4];
    const float* b2 = (const float*)d_in[5];
    float*       out = (float*)d_out;

    const int n = in_sizes[0] / 128;   // 100000
    const int E = in_sizes[1] / 2;     // 1600000
    const int* srcv = ei;
    const int* dstv = ei + E;

    const int NP = 102400;
    float* wsf     = (float*)d_ws;
    float* dinv    = wsf;                                   // NP f32
    int*   row_ptr = (int*)(wsf + NP);                      // NP i32 (n+1 used)
    u32*   ew      = (u32*)(wsf + 2 * NP);                  // E u32
    u32*   h1u     = (u32*)(wsf + 2 * (size_t)NP + (size_t)E);  // n*64 dwords
    float* agg1    = (float*)(h1u + (size_t)n * 64);        // n*128 f32
    u32*   h2u     = h1u;                                   // reuse (n*32 dwords)
    int*   bsum    = (int*)(agg1 + (size_t)n * 128);        // 128 i32
    int*   boff    = bsum + 128;                            // 128 i32
    int*   cnt     = (int*)h1u;     // overlay h1u (dead before gemm1)
    int*   rank    = (int*)agg1;    // overlay agg1 (dead before gather128 writes)

    const int NB = (n + 1023) / 1024;  // 98 scan blocks

    // --- CSR build ---
    zero_i32<<<(n + 255) / 256, 256, 0, stream>>>(cnt, n);
    hist_rank<<<(E + 255) / 256, 256, 0, stream>>>(dstv, cnt, rank, E);
    scan_reduce<<<NB, 1024, 0, stream>>>(cnt, bsum, n);
    scan_partials<<<1, 64, 0, stream>>>(bsum, boff, row_ptr, NB, n);
    scan_apply<<<NB, 1024, 0, stream>>>(cnt, boff, row_ptr, dinv, n);
    place_csr<<<(E + 255) / 256, 256, 0, stream>>>(srcv, dstv, rank, row_ptr, dinv, ew, E);

    const int gblocks = (n + 127) / 128;
    // --- layer 1 ---
    gemm_tiled<128, false><<<gblocks, 256, 0, stream>>>(x, W1, h1u, n);
    gather128<<<(n + 3) / 4, 256, 0, stream>>>(h1u, dinv, row_ptr, ew, b1, agg1, n);

    // --- layer 2 ---
    gemm_tiled<64, true><<<gblocks, 256, 0, stream>>>(agg1, W2, h2u, n);
    gather64<<<(n + 3) / 4, 256, 0, stream>>>(h2u, dinv, row_ptr, ew, b2, out, n);
}

// Round 6
// 369.401 us; speedup vs baseline: 4.8624x; 1.1146x over previous
//
#include <hip/hip_runtime.h>

// GCN 2-layer. R6: bf16-MFMA GEMMs (no LDS, operand-swap epilogue), agg1
// stored as relu'd bf16 (halves gather128 write + gemm2 read).
// CSR build: hist+rank fused, multi-block scan, atomic-free placement,
// 4B edge payload src(17b)|f15-weight. Features bf16-pair packed.

typedef unsigned int u32;
using bfrag = __attribute__((ext_vector_type(8))) short;   // 8 bf16 (4 VGPRs)
using f4    = __attribute__((ext_vector_type(4))) float;   // 4 fp32 acc

__device__ inline u32 pack_bf16(float a, float b) {
    u32 ua = __float_as_uint(a);
    u32 ub = __float_as_uint(b);
    ua += 0x7fffu + ((ua >> 16) & 1u);   // RNE
    ub += 0x7fffu + ((ub >> 16) & 1u);
    return (ua >> 16) | (ub & 0xffff0000u);
}
__device__ inline float bf_lo(u32 v) { return __uint_as_float(v << 16); }
__device__ inline float bf_hi(u32 v) { return __uint_as_float(v & 0xffff0000u); }

// w in (2^-16, 1] -> 15 bits: ec = 127-exp (4b), mantissa 11b
__device__ inline u32 pack_w(float w) {
    u32 b  = __float_as_uint(w) + 0x800u;
    u32 e8 = b >> 23;
    u32 ec = 127u - e8;
    u32 m  = (b >> 12) & 0x7ffu;
    if (ec > 15u) { ec = 15u; m = 0u; }
    return (ec << 11) | m;
}
__device__ inline float dec_w(u32 u) {
    u32 wq = u & 0x7fffu;
    u32 e8 = 127u - (wq >> 11);
    return __uint_as_float((e8 << 23) | ((wq & 0x7ffu) << 12));
}

__device__ inline bfrag as_bfrag(uint4 v) {
    union { uint4 u; bfrag b; } x; x.u = v; return x.b;
}

__global__ void zero_i32(int* __restrict__ p, int n) {
    int i = blockIdx.x * blockDim.x + threadIdx.x;
    if (i < n) p[i] = 0;
}

__global__ void hist_rank(const int* __restrict__ dst, int* __restrict__ cnt,
                          int* __restrict__ rank, int E) {
    int e = blockIdx.x * blockDim.x + threadIdx.x;
    if (e < E) rank[e] = atomicAdd(&cnt[dst[e]], 1);
}

__global__ __launch_bounds__(1024) void scan_reduce(const int* __restrict__ cnt,
                                                    int* __restrict__ bsum, int n) {
    __shared__ int wsum[16];
    int i = blockIdx.x * 1024 + threadIdx.x;
    int v = (i < n) ? cnt[i] : 0;
#pragma unroll
    for (int off = 32; off > 0; off >>= 1) v += __shfl_down(v, off);
    const int lane = threadIdx.x & 63;
    const int wid  = threadIdx.x >> 6;
    if (lane == 0) wsum[wid] = v;
    __syncthreads();
    if (threadIdx.x < 16) {
        int s = wsum[threadIdx.x];
#pragma unroll
        for (int off = 8; off > 0; off >>= 1) s += __shfl_down(s, off);
        if (threadIdx.x == 0) bsum[blockIdx.x] = s;
    }
}

__global__ void scan_partials(const int* __restrict__ bsum, int* __restrict__ boff,
                              int* __restrict__ row_ptr, int nb, int n) {
    const int lane = threadIdx.x;  // 64 threads
    int carry = 0;
    for (int base = 0; base < nb; base += 64) {
        int i = base + lane;
        int v = (i < nb) ? bsum[i] : 0;
        int x = v;
#pragma unroll
        for (int off = 1; off < 64; off <<= 1) {
            int t = __shfl_up(x, off);
            if (lane >= off) x += t;
        }
        if (i < nb) boff[i] = carry + x - v;
        carry += __shfl(x, 63);
    }
    if (lane == 0) row_ptr[n] = carry;
}

__global__ __launch_bounds__(1024) void scan_apply(const int* __restrict__ cnt,
                                                   const int* __restrict__ boff,
                                                   int* __restrict__ row_ptr,
                                                   float* __restrict__ dinv, int n) {
    __shared__ int wsum[16];
    const int lane = threadIdx.x & 63;
    const int wid  = threadIdx.x >> 6;
    int i = blockIdx.x * 1024 + threadIdx.x;
    int v = (i < n) ? cnt[i] : 0;
    int x = v;
#pragma unroll
    for (int off = 1; off < 64; off <<= 1) {
        int t = __shfl_up(x, off);
        if (lane >= off) x += t;
    }
    if (lane == 63) wsum[wid] = x;
    __syncthreads();
    if (wid == 0 && lane < 16) {
        int w = wsum[lane];
#pragma unroll
        for (int off = 1; off < 16; off <<= 1) {
            int t = __shfl_up(w, off);
            if (lane >= off) w += t;
        }
        wsum[lane] = w;
    }
    __syncthreads();
    int wave_excl = (wid == 0) ? 0 : wsum[wid - 1];
    if (i < n) {
        row_ptr[i] = boff[blockIdx.x] + wave_excl + (x - v);
        dinv[i]    = rsqrtf((float)v + 1.0f);
    }
}

__global__ void place_csr(const int* __restrict__ src, const int* __restrict__ dst,
                          const int* __restrict__ rank, const int* __restrict__ row_ptr,
                          const float* __restrict__ dinv, u32* __restrict__ ew, int E) {
    int e = blockIdx.x * blockDim.x + threadIdx.x;
    if (e < E) {
        int s = src[e];
        int d = dst[e];
        float w = dinv[s] * dinv[d];
        ew[row_ptr[d] + rank[e]] = ((u32)s << 15) | pack_w(w);
    }
}

// W1[128][128], W2[128][64] fp32 -> Wt bf16-pair packed, transposed:
// W1t[nr][kd] = pack(W1[2kd][nr], W1[2kd+1][nr]); same for W2t.
__global__ void prep_w(const float* __restrict__ W1, const float* __restrict__ W2,
                       u32* __restrict__ W1t, u32* __restrict__ W2t) {
    int idx = blockIdx.x * 256 + threadIdx.x;
    if (idx < 128 * 64) {
        int nr = idx >> 6, kd = idx & 63;
        W1t[idx] = pack_bf16(W1[(2 * kd) * 128 + nr], W1[(2 * kd + 1) * 128 + nr]);
    } else if (idx < 128 * 64 + 64 * 64) {
        int i = idx - 128 * 64;
        int nr = i >> 6, kd = i & 63;
        W2t[i] = pack_bf16(W2[(2 * kd) * 64 + nr], W2[(2 * kd + 1) * 64 + nr]);
    }
}

// C[n][OUT] bf16-packed = A[n][128] @ W[128][OUT], via 16x16x32 bf16 MFMA.
// No LDS. Wave handles 32 rows (2 m-frags). Operand swap: mfma(w_frag, a_frag)
// -> D tile = C^T layout: C-row = lane&15, C-col = nt*16 + quad*4 + reg, so
// each lane holds 4 consecutive C-cols -> one uint2 store per tile.
// ABF: A is bf16-pair packed [n][64] dwords; else fp32 [n][128].
template <int OUT, bool ABF>
__global__ __launch_bounds__(256) void gemm_mfma(const void* __restrict__ Ap,
                                                 const u32* __restrict__ Wt,
                                                 u32* __restrict__ C, int n) {
    constexpr int NT = OUT / 16;
    const int lane = threadIdx.x & 63;
    const int wv   = threadIdx.x >> 6;
    const int r15  = lane & 15;
    const int quad = lane >> 4;
    const int rowbase = blockIdx.x * 128 + wv * 32;

    // A fragments: af[mi][ks], lane holds A[row][k = ks*32 + quad*8 + j]
    bfrag af[2][4];
#pragma unroll
    for (int mi = 0; mi < 2; ++mi) {
        int row = rowbase + mi * 16 + r15;
        row = (row < n) ? row : (n - 1);
        if constexpr (ABF) {
            const u32* ar = (const u32*)Ap + (size_t)row * 64 + quad * 4;
#pragma unroll
            for (int ks = 0; ks < 4; ++ks)
                af[mi][ks] = as_bfrag(*(const uint4*)(ar + ks * 16));
        } else {
            const float* arf = (const float*)Ap + (size_t)row * 128 + quad * 8;
#pragma unroll
            for (int ks = 0; ks < 4; ++ks) {
                float4 v0 = *(const float4*)(arf + ks * 32);
                float4 v1 = *(const float4*)(arf + ks * 32 + 4);
                uint4 p;
                p.x = pack_bf16(v0.x, v0.y);
                p.y = pack_bf16(v0.z, v0.w);
                p.z = pack_bf16(v1.x, v1.y);
                p.w = pack_bf16(v1.z, v1.w);
                af[mi][ks] = as_bfrag(p);
            }
        }
    }

    f4 acc[2][NT];
#pragma unroll
    for (int mi = 0; mi < 2; ++mi)
#pragma unroll
        for (int nt = 0; nt < NT; ++nt) acc[mi][nt] = (f4)0.0f;

#pragma unroll
    for (int nt = 0; nt < NT; ++nt) {
        const u32* wr = Wt + (size_t)(nt * 16 + r15) * 64 + quad * 4;
#pragma unroll
        for (int ks = 0; ks < 4; ++ks) {
            bfrag bf = as_bfrag(*(const uint4*)(wr + ks * 16));
            acc[0][nt] = __builtin_amdgcn_mfma_f32_16x16x32_bf16(bf, af[0][ks], acc[0][nt], 0, 0, 0);
            acc[1][nt] = __builtin_amdgcn_mfma_f32_16x16x32_bf16(bf, af[1][ks], acc[1][nt], 0, 0, 0);
        }
    }

#pragma unroll
    for (int mi = 0; mi < 2; ++mi) {
        int row = rowbase + mi * 16 + r15;
        if (row < n) {
            u32* cp = C + (size_t)row * (OUT / 2);
#pragma unroll
            for (int nt = 0; nt < NT; ++nt) {
                uint2 p;
                p.x = pack_bf16(acc[mi][nt][0], acc[mi][nt][1]);
                p.y = pack_bf16(acc[mi][nt][2], acc[mi][nt][3]);
                *(uint2*)(cp + nt * 8 + quad * 2) = p;
            }
        }
    }
}

// Layer-1 gather: one wave per node, F=128, h bf16-pair packed [n][64] dwords.
// Epilogue: relu + pack bf16 -> agg1b (gemm2 input).
__global__ __launch_bounds__(256) void gather128(const u32* __restrict__ h,
                                                 const float* __restrict__ dinv,
                                                 const int* __restrict__ row_ptr,
                                                 const u32* __restrict__ ew,
                                                 const float* __restrict__ bias,
                                                 u32* __restrict__ outp, int n) {
    const int lane = threadIdx.x & 63;
    const int node = blockIdx.x * 4 + (threadIdx.x >> 6);
    if (node >= n) return;

    const float dd  = dinv[node];
    const int   beg = row_ptr[node];
    const int   end = row_ptr[node + 1];

    u32 sv = h[(size_t)node * 64 + lane];
    float2 b = ((const float2*)bias)[lane];
    float acc0 = fmaf(bf_lo(sv) * dd, dd, b.x);
    float acc1 = fmaf(bf_hi(sv) * dd, dd, b.y);

    for (int j = beg; j < end; j += 4) {
        int i1 = (j + 1 < end) ? j + 1 : end - 1;
        int i2 = (j + 2 < end) ? j + 2 : end - 1;
        int i3 = (j + 3 < end) ? j + 3 : end - 1;
        u32 e0 = ew[j];
        u32 e1 = ew[i1];
        u32 e2 = ew[i2];
        u32 e3 = ew[i3];
        float w0 = dec_w(e0);
        float w1 = (j + 1 < end) ? dec_w(e1) : 0.0f;
        float w2 = (j + 2 < end) ? dec_w(e2) : 0.0f;
        float w3 = (j + 3 < end) ? dec_w(e3) : 0.0f;
        u32 v0 = h[(size_t)(e0 >> 15) * 64 + lane];
        u32 v1 = h[(size_t)(e1 >> 15) * 64 + lane];
        u32 v2 = h[(size_t)(e2 >> 15) * 64 + lane];
        u32 v3 = h[(size_t)(e3 >> 15) * 64 + lane];
        acc0 = fmaf(w0, bf_lo(v0), acc0); acc1 = fmaf(w0, bf_hi(v0), acc1);
        acc0 = fmaf(w1, bf_lo(v1), acc0); acc1 = fmaf(w1, bf_hi(v1), acc1);
        acc0 = fmaf(w2, bf_lo(v2), acc0); acc1 = fmaf(w2, bf_hi(v2), acc1);
        acc0 = fmaf(w3, bf_lo(v3), acc0); acc1 = fmaf(w3, bf_hi(v3), acc1);
    }

    // relu + bf16 pack (relu commutes with RNE quantization)
    outp[(size_t)node * 64 + lane] = pack_bf16(fmaxf(acc0, 0.0f), fmaxf(acc1, 0.0f));
}

// Layer-2 gather: one wave per node, F=64, 2 edges per wave-step. fp32 out.
__global__ __launch_bounds__(256) void gather64(const u32* __restrict__ h,
                                                const float* __restrict__ dinv,
                                                const int* __restrict__ row_ptr,
                                                const u32* __restrict__ ew,
                                                const float* __restrict__ bias,
                                                float* __restrict__ outp, int n) {
    const int lane   = threadIdx.x & 63;
    const int lane32 = lane & 31;
    const int sub    = lane >> 5;
    const int node   = blockIdx.x * 4 + (threadIdx.x >> 6);
    if (node >= n) return;

    const float dd  = dinv[node];
    const int   beg = row_ptr[node];
    const int   end = row_ptr[node + 1];

    float acc0 = 0.0f, acc1 = 0.0f;
    if (sub == 0) {
        u32 sv = h[(size_t)node * 32 + lane32];
        float2 b = ((const float2*)bias)[lane32];
        acc0 = fmaf(bf_lo(sv) * dd, dd, b.x);
        acc1 = fmaf(bf_hi(sv) * dd, dd, b.y);
    }

    for (int j = beg; j < end; j += 4) {
        int i0 = j + sub;
        int i1 = j + 2 + sub;
        int c0 = (i0 < end) ? i0 : end - 1;
        int c1 = (i1 < end) ? i1 : end - 1;
        u32 e0 = ew[c0];
        u32 e1 = ew[c1];
        float w0 = (i0 < end) ? dec_w(e0) : 0.0f;
        float w1 = (i1 < end) ? dec_w(e1) : 0.0f;
        u32 v0 = h[(size_t)(e0 >> 15) * 32 + lane32];
        u32 v1 = h[(size_t)(e1 >> 15) * 32 + lane32];
        acc0 = fmaf(w0, bf_lo(v0), acc0); acc1 = fmaf(w0, bf_hi(v0), acc1);
        acc0 = fmaf(w1, bf_lo(v1), acc0); acc1 = fmaf(w1, bf_hi(v1), acc1);
    }

    acc0 += __shfl_xor(acc0, 32);
    acc1 += __shfl_xor(acc1, 32);
    if (sub == 0)
        ((float2*)(outp + (size_t)node * 64))[lane32] = make_float2(acc0, acc1);
}

extern "C" void kernel_launch(void* const* d_in, const int* in_sizes, int n_in,
                              void* d_out, int out_size, void* d_ws, size_t ws_size,
                              hipStream_t stream) {
    const float* x  = (const float*)d_in[0];
    const int*   ei = (const int*)d_in[1];
    const float* W1 = (const float*)d_in[2];
    const float* b1 = (const float*)d_in[3];
    const float* W2 = (const float*)d_in[4];
    const float* b2 = (const float*)d_in[5];
    float*       out = (float*)d_out;

    const int n = in_sizes[0] / 128;   // 100000
    const int E = in_sizes[1] / 2;     // 1600000
    const int* srcv = ei;
    const int* dstv = ei + E;

    const int NP = 102400;
    u32* wsd = (u32*)d_ws;
    float* dinv    = (float*)wsd;                        // NP
    int*   row_ptr = (int*)(wsd + NP);                   // NP
    u32*   ew      = wsd + 2 * (size_t)NP;               // E
    u32*   h1u     = ew + E;                             // n*64 (gemm1 C / gather128 in)
    u32*   agg1b   = h1u + (size_t)n * 64;               // n*64 (gather128 out / gemm2 A)
    u32*   W1t     = agg1b + (size_t)n * 64;             // 8192
    u32*   W2t     = W1t + 8192;                         // 4096
    int*   bsum    = (int*)(W2t + 4096);                 // 128
    int*   boff    = bsum + 128;                         // 128
    u32*   h2u     = h1u;                                // gemm2 C: n*32, reuses h1u
    int*   cnt     = (int*)h1u;    // overlay: dead before gemm1 writes h1u
    int*   rank    = (int*)agg1b;  // overlay: dead before gather128 writes agg1b

    const int NB = (n + 1023) / 1024;

    // --- CSR build ---
    zero_i32<<<(n + 255) / 256, 256, 0, stream>>>(cnt, n);
    hist_rank<<<(E + 255) / 256, 256, 0, stream>>>(dstv, cnt, rank, E);
    scan_reduce<<<NB, 1024, 0, stream>>>(cnt, bsum, n);
    scan_partials<<<1, 64, 0, stream>>>(bsum, boff, row_ptr, NB, n);
    scan_apply<<<NB, 1024, 0, stream>>>(cnt, boff, row_ptr, dinv, n);
    place_csr<<<(E + 255) / 256, 256, 0, stream>>>(srcv, dstv, rank, row_ptr, dinv, ew, E);

    // --- weights to bf16, transposed ---
    prep_w<<<48, 256, 0, stream>>>(W1, W2, W1t, W2t);

    const int gblocks = (n + 127) / 128;  // 782
    // --- layer 1 ---
    gemm_mfma<128, false><<<gblocks, 256, 0, stream>>>(x, W1t, h1u, n);
    gather128<<<(n + 3) / 4, 256, 0, stream>>>(h1u, dinv, row_ptr, ew, b1, agg1b, n);

    // --- layer 2 ---
    gemm_mfma<64, true><<<gblocks, 256, 0, stream>>>(agg1b, W2t, h2u, n);
    gather64<<<(n + 3) / 4, 256, 0, stream>>>(h2u, dinv, row_ptr, ew, b2, out, n);
}